// Round 1
// 264.581 us; speedup vs baseline: 1.0045x; 1.0045x over previous
//
#include <hip/hip_runtime.h>
#include <math.h>

// SSM_18597208391915: HiPPO-LegT recurrence, O(N) semiseparable solve.
// Ad = (I-cA)^{-1}(I+cA) = 2M - I  =>  h' = tanh(2*M(h + c*u*P) - h).
// R11: issue-count reduction on the R10 NW=4 skewed-wave pipeline.
//   (1) state m = c2*h (c2 = 2*log2e): w = fma(upc,u,m); no au/negh.
//   (2) per-element exclusive-prefix fully constant-folded (fp64 setup):
//       g_i = ka_i*Tent + t_i0*w0 + t_i1*w1 + t_i2*w2 + base_i
//       kills gam/Tb/Tn/tmp pk-chains and all v2f broadcast movs.
//   (3) one shared v_rcp for 4 sigmoids: r_i = prod_{j!=i}t_j * rcp(prod t_j),
//       g clamped at 30 so P = prod(1+e_i) <= 2^120 (no overflow; clamp error
//       < 2e-9 in h). Cuts 8 trans/step -> 5.
//   (4) bound_ctrl=1 DPP for the 5 zero-fill shifts (drops old-movs / enables
//       v_fmac_dpp fusion). Masked-row bcast levels keep explicit old=0.
// R10 mechanics retained verbatim: 16-step register inner loop, one barrier
// per chunk, float4 LDS edge comms, fp64 Phi composition, 2 waves/SIMD.

#define SEQ     784
#define OUT_DIM 10
#define NW      4
#define CH      16            // steps per chunk
#define NCH     (SEQ/CH)      // 49
#define EPL     4             // elems/lane: NW*64*EPL = 1024 = HIDDEN

#if __has_builtin(__builtin_amdgcn_exp2f)
#define EXP2F(x) __builtin_amdgcn_exp2f(x)
#else
#define EXP2F(x) __expf(0.69314718055994531f * (x))
#endif

// DPP move with explicit old: masked/invalid lanes get `old`.
template<int CTRL, int ROW_MASK>
__device__ __forceinline__ float dpp_mov(float src, float old) {
    return __int_as_float(__builtin_amdgcn_update_dpp(
        __float_as_int(old), __float_as_int(src), CTRL, ROW_MASK, 0xf, false));
}
// DPP move, bound_ctrl:0 — invalid lanes read 0, full row/bank mask.
// old operand is dead -> compiler can emit a single v_mov_b32_dpp (or fuse).
template<int CTRL>
__device__ __forceinline__ float dpp_bc0(float src) {
    return __int_as_float(__builtin_amdgcn_update_dpp(
        0, __float_as_int(src), CTRL, 0xf, 0xf, true));
}
// ctrls: row_shr:N = 0x110|N, row_bcast15 = 0x142, row_bcast31 = 0x143,
//        wave_shr:1 = 0x138

__global__ __launch_bounds__(256, 2)
void ssm_hippo_scan(const float* __restrict__ x,     // (512, 784)
                    const float* __restrict__ C,     // (1024)
                    const float* __restrict__ W,     // (10)
                    const float* __restrict__ bvec,  // (10)
                    float* __restrict__ out)         // (512, 10)
{
    const int b    = blockIdx.x;
    const int tid  = threadIdx.x;
    const int wv   = tid >> 6;       // wave w owns elems [w*256, w*256+256)
    const int lane = tid & 63;

    __shared__ __align__(16) float u_s[SEQ];
    __shared__ __align__(16) float totB_s[NW-1][SEQ]; // inclusive-B streams
    __shared__ double part_s[NW];

    for (int t = tid; t < SEQ; t += 256) u_s[t] = x[b * SEQ + t];

    const double hdt  = 0.5 / (double)SEQ;            // c = dt/2
    const double L2E2 = 2.0 * 1.4426950408889634;     // 2*log2(e)

    // ---- per-element constants (n = wv*256 + lane*EPL + i), fp64-derived.
    // Semantics (w = m + upc*u, m = c2*h, S = cross-elem prefix scaled by c2):
    //   S_{n+1} = alpha_n S_n + pdin_n w_n ; g_n = ivd_n w_n - m_n - hp_n S_n
    //   S_i(entering elem i) = aprod_i*Tent + Tb_i(local w's)
    float upc[EPL], ivd[EPL], ka[EPL], cB[EPL];
    float t10, t20, t21, t30, t31, t32;
    float Alev0, Alev1, Alev2, Alev3, Alev4, Alev5, Aexcl;
    float c2, n2c2;
    {
        double p[EPL], d[EPL], a[EPL], pdin[EPL], hp[EPL];
#pragma unroll
        for (int i = 0; i < EPL; ++i) {
            const int n = wv * 256 + lane * EPL + i;
            p[i]    = sqrt(1.0 + 2.0 * (double)n);
            d[i]    = 1.0 + hdt * (double)(n + 1);
            a[i]    = 1.0 - hdt * p[i] * p[i] / d[i];
            pdin[i] = p[i] / d[i];
            hp[i]   = 2.0 * hdt * p[i] / d[i];
            upc[i]  = (float)(L2E2 * hdt * p[i]);
            ivd[i]  = (float)(2.0 / d[i]);
        }
        const double ap0 = 1.0, ap1 = a[0], ap2 = a[0]*a[1], ap3 = a[0]*a[1]*a[2];
        ka[0] = (float)(-hp[0] * ap0);
        ka[1] = (float)(-hp[1] * ap1);
        ka[2] = (float)(-hp[2] * ap2);
        ka[3] = (float)(-hp[3] * ap3);
        // lane-inclusive B = sum_j cB_j * w_j
        cB[0] = (float)(a[1]*a[2]*a[3] * pdin[0]);
        cB[1] = (float)(a[2]*a[3] * pdin[1]);
        cB[2] = (float)(a[3] * pdin[2]);
        cB[3] = (float)(pdin[3]);
        // -hp_i * (coefficient of w_j in Tb_i)
        t10 = (float)(-hp[1] * pdin[0]);
        t20 = (float)(-hp[2] * a[1] * pdin[0]);
        t21 = (float)(-hp[2] * pdin[1]);
        t30 = (float)(-hp[3] * a[2] * a[1] * pdin[0]);
        t31 = (float)(-hp[3] * a[2] * pdin[1]);
        t32 = (float)(-hp[3] * pdin[2]);

        float A = (float)(a[0]*a[1]*a[2]*a[3]);   // per-lane decay
        Alev0 = A; A *= dpp_mov<0x111, 0xf>(A, 1.0f);
        Alev1 = A; A *= dpp_mov<0x112, 0xf>(A, 1.0f);
        Alev2 = A; A *= dpp_mov<0x114, 0xf>(A, 1.0f);
        Alev3 = A; A *= dpp_mov<0x118, 0xf>(A, 1.0f);
        Alev4 = A; A *= dpp_mov<0x142, 0xa>(A, 1.0f);
        Alev5 = A; A *= dpp_mov<0x143, 0xc>(A, 1.0f);
        Aexcl = dpp_mov<0x138, 0xf>(A, 1.0f);     // lane0 -> 1 (excl prod)

        c2   = (float)L2E2;
        n2c2 = (float)(-2.0 * L2E2);
    }

    // inter-wave composition coefficients (closed-form Phi products, fp64)
    float cF1 = 0.0f, cF2 = 0.0f, cF12 = 0.0f;
    {
        double n1 = 1.0, d1 = 1.0, n2 = 1.0, d2 = 1.0;
        for (int n = 256; n < 512; ++n) {
            n1 *= 1.0 - hdt * (double)n; d1 *= 1.0 + hdt * (double)(n + 1);
        }
        for (int n = 512; n < 768; ++n) {
            n2 *= 1.0 - hdt * (double)n; d2 *= 1.0 + hdt * (double)(n + 1);
        }
        const double Phi1 = n1 / d1, Phi2 = n2 / d2;
        cF1 = (float)Phi1; cF2 = (float)Phi2; cF12 = (float)(Phi1 * Phi2);
    }

    __syncthreads();                         // u_s ready

    // ---- state: m = c2 * h   (h = 0 -> m = 0)
    float m0 = 0.0f, m1 = 0.0f, m2 = 0.0f, m3 = 0.0f;

#pragma unroll 1
    for (int tick = 0; tick < NCH + NW - 1; ++tick) {
        const int ch = tick - wv;            // this wave's chunk index
        if (0 <= ch && ch < NCH) {
            // ---- bulk register loads: u's and incoming-B composition
            float4 u4[CH/4];
            float  Tin[CH];
            {
                const float4* up = (const float4*)&u_s[ch * CH];
#pragma unroll
                for (int q = 0; q < CH/4; ++q) u4[q] = up[q];
            }
            if (wv == 0) {
#pragma unroll
                for (int k = 0; k < CH; ++k) Tin[k] = 0.0f;
            } else if (wv == 1) {
                const float4* b0 = (const float4*)&totB_s[0][ch * CH];
#pragma unroll
                for (int q = 0; q < CH/4; ++q) {
                    const float4 v0 = b0[q];
                    Tin[4*q+0] = v0.x; Tin[4*q+1] = v0.y;
                    Tin[4*q+2] = v0.z; Tin[4*q+3] = v0.w;
                }
            } else if (wv == 2) {
                const float4* b0 = (const float4*)&totB_s[0][ch * CH];
                const float4* b1 = (const float4*)&totB_s[1][ch * CH];
#pragma unroll
                for (int q = 0; q < CH/4; ++q) {
                    const float4 v0 = b0[q], v1 = b1[q];
                    Tin[4*q+0] = fmaf(cF1, v0.x, v1.x);
                    Tin[4*q+1] = fmaf(cF1, v0.y, v1.y);
                    Tin[4*q+2] = fmaf(cF1, v0.z, v1.z);
                    Tin[4*q+3] = fmaf(cF1, v0.w, v1.w);
                }
            } else {
                const float4* b0 = (const float4*)&totB_s[0][ch * CH];
                const float4* b1 = (const float4*)&totB_s[1][ch * CH];
                const float4* b2 = (const float4*)&totB_s[2][ch * CH];
#pragma unroll
                for (int q = 0; q < CH/4; ++q) {
                    const float4 v0 = b0[q], v1 = b1[q], v2 = b2[q];
                    Tin[4*q+0] = fmaf(cF12, v0.x, fmaf(cF2, v1.x, v2.x));
                    Tin[4*q+1] = fmaf(cF12, v0.y, fmaf(cF2, v1.y, v2.y));
                    Tin[4*q+2] = fmaf(cF12, v0.z, fmaf(cF2, v1.z, v2.z));
                    Tin[4*q+3] = fmaf(cF12, v0.w, fmaf(cF2, v1.w, v2.w));
                }
            }
            float Bacc[CH];

#pragma unroll
            for (int k = 0; k < CH; ++k) {
                const float u = ((const float*)&u4[k>>2])[k&3];

                // ---- head: w_i = upc_i*u + m_i   (m = c2*h)
                const float w0 = fmaf(upc[0], u, m0);
                const float w1 = fmaf(upc[1], u, m1);
                const float w2 = fmaf(upc[2], u, m2);
                const float w3 = fmaf(upc[3], u, m3);

                // ---- lane-inclusive affine-B directly from w's
                float B = fmaf(cB[0], w0,
                          fmaf(cB[1], w1,
                          fmaf(cB[2], w2, cB[3] * w3)));

                // ---- cross-lane affine scan (A's precomputed)
                float Bin;
                Bin = dpp_bc0<0x111>(B);            B = fmaf(Alev0, Bin, B);
                Bin = dpp_bc0<0x112>(B);            B = fmaf(Alev1, Bin, B);
                Bin = dpp_bc0<0x114>(B);            B = fmaf(Alev2, Bin, B);
                Bin = dpp_bc0<0x118>(B);            B = fmaf(Alev3, Bin, B);
                Bin = dpp_mov<0x142, 0xa>(B, 0.0f); B = fmaf(Alev4, Bin, B);
                Bin = dpp_mov<0x143, 0xc>(B, 0.0f); B = fmaf(Alev5, Bin, B);
                Bacc[k] = B;                        // publish later

                const float Tst  = dpp_bc0<0x138>(B);        // excl shift
                const float Tent = fmaf(Aexcl, Tin[k], Tst); // lane entry S

                // ---- flattened per-element g (exponent of sigmoid):
                // g_i = ka_i*Tent + sum_{j<i} t_ij*w_j + (ivd_i*w_i - m_i)
                const float b0g = fmaf(ivd[0], w0, -m0);
                const float b1g = fmaf(ivd[1], w1, -m1);
                const float b2g = fmaf(ivd[2], w2, -m2);
                const float b3g = fmaf(ivd[3], w3, -m3);
                const float g0 = fmaf(ka[0], Tent, b0g);
                const float g1 = fmaf(ka[1], Tent, fmaf(t10, w0, b1g));
                const float g2 = fmaf(ka[2], Tent,
                                 fmaf(t20, w0, fmaf(t21, w1, b2g)));
                const float g3 = fmaf(ka[3], Tent,
                                 fmaf(t30, w0,
                                 fmaf(t31, w1, fmaf(t32, w2, b3g))));

                // ---- sigmoid tail: clamp (so quad product can't overflow),
                // 4 exp2, ONE shared rcp for all four 1/(1+e).
                const float e0 = EXP2F(fminf(g0, 30.0f));
                const float e1 = EXP2F(fminf(g1, 30.0f));
                const float e2 = EXP2F(fminf(g2, 30.0f));
                const float e3 = EXP2F(fminf(g3, 30.0f));
                const float q0 = e0 + 1.0f, q1 = e1 + 1.0f;
                const float q2 = e2 + 1.0f, q3 = e3 + 1.0f;
                const float p01 = q0 * q1, p23 = q2 * q3;
                const float ip  = __builtin_amdgcn_rcpf(p01 * p23);
                const float i01 = p23 * ip;          // 1/(q0*q1)
                const float i23 = p01 * ip;          // 1/(q2*q3)
                // r_i = 1/q_i ; m' = c2 - 2*c2*r = c2*h'
                m0 = fmaf(n2c2, q1 * i01, c2);
                m1 = fmaf(n2c2, q0 * i01, c2);
                m2 = fmaf(n2c2, q3 * i23, c2);
                m3 = fmaf(n2c2, q2 * i23, c2);
            }

            // publish this wave's chunk B-totals (lane 63 holds them)
            if (wv < NW - 1 && lane == 63) {
                float4* tp = (float4*)&totB_s[wv][ch * CH];
#pragma unroll
                for (int q = 0; q < CH/4; ++q)
                    tp[q] = make_float4(Bacc[4*q], Bacc[4*q+1],
                                        Bacc[4*q+2], Bacc[4*q+3]);
            }
        }
        __syncthreads();   // one barrier per CHUNK (16 steps)
    }

    // ---- epilogue: h = m/c2; tot = dot(h, C) over this wave's 256 elems
    double acc = 0.0;
    {
        const int base = wv * 256 + lane * EPL;
        acc = fma((double)C[base + 0], (double)m0, acc);
        acc = fma((double)C[base + 1], (double)m1, acc);
        acc = fma((double)C[base + 2], (double)m2, acc);
        acc = fma((double)C[base + 3], (double)m3, acc);
    }
#pragma unroll
    for (int off = 32; off > 0; off >>= 1)
        acc += __shfl_down(acc, off, 64);
    if (lane == 0) part_s[wv] = acc;
    __syncthreads();
    if (tid < OUT_DIM) {
        // scale by 1/c2 = ln2/2 once, in fp64
        const double tot = (part_s[0] + part_s[1] + part_s[2] + part_s[3])
                         * 0.34657359027997264;
        out[b * OUT_DIM + tid] =
            (float)fma(tot, (double)W[tid], (double)bvec[tid]);
    }
}

extern "C" void kernel_launch(void* const* d_in, const int* in_sizes, int n_in,
                              void* d_out, int out_size, void* d_ws, size_t ws_size,
                              hipStream_t stream) {
    const float* x  = (const float*)d_in[0];   // (512, 784, 1)
    const float* C  = (const float*)d_in[1];   // (1, 1024)
    const float* W  = (const float*)d_in[2];   // (1, 10)
    const float* bv = (const float*)d_in[3];   // (10,)
    float* out      = (float*)d_out;           // (512, 10)
    hipLaunchKernelGGL(ssm_hippo_scan, dim3(512), dim3(256), 0, stream,
                       x, C, W, bv, out);
}